// Round 1
// baseline (244.618 us; speedup 1.0000x reference)
//
#include <hip/hip_runtime.h>
#include <math.h>

// Problem constants (SCDM_89318139888190)
#define Bdim 8
#define Fdim 256
#define Tdim 32
#define Ddim 1024
#define NEGV (-1e30f)

__device__ __forceinline__ float fast_tanh(float x) {
    // tanh(x) = 1 - 2/(exp(2x)+1); saturates correctly at +-1
    float e = __expf(2.0f * x);
    return 1.0f - 2.0f / (e + 1.0f);
}

// ---------------------------------------------------------------------------
// fp32 tiled GEMM: C[M,N] = A[M,K] * B[K,N] (+ bias[N] if bias != nullptr)
// BM=BN=64, BK=16, 256 threads, 4x4 micro-tile per thread.
// ---------------------------------------------------------------------------
#define BM 64
#define BN 64
#define BK 16

__global__ __launch_bounds__(256) void gemm_f32(
    const float* __restrict__ A, const float* __restrict__ B,
    float* __restrict__ C, const float* __restrict__ bias,
    int M, int N, int K)
{
    __shared__ float As[BK][BM];
    __shared__ float Bs[BK][BN];

    const int tid = threadIdx.x;
    const int rowBase = blockIdx.y * BM;
    const int colBase = blockIdx.x * BN;

    // A-load indices: each thread loads one float4 along K
    const int ar = tid >> 2;          // 0..63 (row within tile)
    const int ak = (tid & 3) << 2;    // 0,4,8,12 (k within tile)
    // B-load indices: each thread loads one float4 along N
    const int bk = tid >> 4;          // 0..15 (k within tile)
    const int bc = (tid & 15) << 2;   // 0..60 (col within tile)

    const int ty = tid >> 4;          // 0..15 -> rows ty*4..ty*4+3
    const int tx = tid & 15;          // 0..15 -> cols tx*4..tx*4+3

    float acc[4][4];
    #pragma unroll
    for (int i = 0; i < 4; ++i)
        #pragma unroll
        for (int j = 0; j < 4; ++j) acc[i][j] = 0.0f;

    for (int k0 = 0; k0 < K; k0 += BK) {
        float4 av = *(const float4*)(A + (size_t)(rowBase + ar) * K + k0 + ak);
        As[ak + 0][ar] = av.x;
        As[ak + 1][ar] = av.y;
        As[ak + 2][ar] = av.z;
        As[ak + 3][ar] = av.w;
        float4 bv = *(const float4*)(B + (size_t)(k0 + bk) * N + colBase + bc);
        *(float4*)&Bs[bk][bc] = bv;
        __syncthreads();

        #pragma unroll
        for (int k = 0; k < BK; ++k) {
            float4 a4 = *(const float4*)&As[k][ty * 4];
            float4 b4 = *(const float4*)&Bs[k][tx * 4];
            float aa[4] = {a4.x, a4.y, a4.z, a4.w};
            float bb[4] = {b4.x, b4.y, b4.z, b4.w};
            #pragma unroll
            for (int i = 0; i < 4; ++i)
                #pragma unroll
                for (int j = 0; j < 4; ++j)
                    acc[i][j] = fmaf(aa[i], bb[j], acc[i][j]);
        }
        __syncthreads();
    }

    #pragma unroll
    for (int i = 0; i < 4; ++i) {
        int row = rowBase + ty * 4 + i;
        int col = colBase + tx * 4;
        float4 o;
        o.x = acc[i][0]; o.y = acc[i][1]; o.z = acc[i][2]; o.w = acc[i][3];
        if (bias != nullptr) {
            o.x += bias[col + 0];
            o.y += bias[col + 1];
            o.z += bias[col + 2];
            o.w += bias[col + 3];
        }
        *(float4*)(C + (size_t)row * N + col) = o;
    }
}

// ---------------------------------------------------------------------------
// Fused additive-attention + conditioning. One block per (b,f).
//   rho[t]  = sum_d tanh(tp[b,t,d] + fp[b,f,d]) * w[d]
//   att     = softmax(rho + (1-qmask)*NEG)
//   txt_h   = sum_t att[t] * txt[b,t,:]
//   w_s     = tanh(txt_h . Wcw + bcw);  b_s = tanh(txt_h . Wcb + bcb)
//   out     = w_s * features + b_s
// ---------------------------------------------------------------------------
__global__ __launch_bounds__(256) void attn_fused(
    const float* __restrict__ feat,   // [B,F,D]
    const float* __restrict__ txt,    // [B,T,D]
    const int*   __restrict__ qmask,  // [B,T]
    const float* __restrict__ fp,     // [B*F,D] feat_proj
    const float* __restrict__ tp,     // [B*T,D] txt_proj + b
    const float* __restrict__ wvec,   // [D]
    const float* __restrict__ Wcw,    // [D]
    const float* __restrict__ bcw,    // [1]
    const float* __restrict__ Wcb,    // [D]
    const float* __restrict__ bcb,    // [1]
    float* __restrict__ out)          // [B,F,D]
{
    const int blk  = blockIdx.x;          // 0 .. B*F-1
    const int b    = blk >> 8;            // / Fdim (256)
    const int tid  = threadIdx.x;
    const int lane = tid & 63;
    const int wave = tid >> 6;            // 0..3

    __shared__ float fp_lds[Ddim];
    __shared__ float w_lds[Ddim];
    __shared__ float rho[Tdim];
    __shared__ float att[Tdim];
    __shared__ float redw[4];
    __shared__ float redb[4];

    const float* fprow = fp + (size_t)blk * Ddim;
    // stage feat_proj row + w into LDS
    {
        int d = tid * 4;   // 256 threads * 4 = 1024 exactly
        *(float4*)&fp_lds[d] = *(const float4*)&fprow[d];
        *(float4*)&w_lds[d]  = *(const float4*)&wvec[d];
    }
    __syncthreads();

    // ---- logits: each wave handles 8 t values ----
    const float* tpb = tp + (size_t)b * Tdim * Ddim;
    #pragma unroll
    for (int tt = 0; tt < 8; ++tt) {
        const int t = wave * 8 + tt;
        const float* tr = tpb + (size_t)t * Ddim;
        float s = 0.0f;
        #pragma unroll
        for (int it = 0; it < 4; ++it) {
            int d0 = lane * 4 + it * 256;
            float4 tv = *(const float4*)&tr[d0];
            float4 fv = *(const float4*)&fp_lds[d0];
            float4 wv = *(const float4*)&w_lds[d0];
            s = fmaf(fast_tanh(tv.x + fv.x), wv.x, s);
            s = fmaf(fast_tanh(tv.y + fv.y), wv.y, s);
            s = fmaf(fast_tanh(tv.z + fv.z), wv.z, s);
            s = fmaf(fast_tanh(tv.w + fv.w), wv.w, s);
        }
        #pragma unroll
        for (int off = 32; off; off >>= 1) s += __shfl_xor(s, off, 64);
        if (lane == 0) rho[t] = s;
    }
    __syncthreads();

    // ---- mask + softmax (serial in thread 0; 32 elements, negligible) ----
    if (tid < Tdim) {
        float q = (float)qmask[b * Tdim + tid];
        rho[tid] += (1.0f - q) * NEGV;
    }
    __syncthreads();
    if (tid == 0) {
        float m = -3.4e38f;
        #pragma unroll
        for (int t = 0; t < Tdim; ++t) m = fmaxf(m, rho[t]);
        float ssum = 0.0f;
        #pragma unroll
        for (int t = 0; t < Tdim; ++t) {
            float e = __expf(rho[t] - m);
            att[t] = e;
            ssum += e;
        }
        float inv = 1.0f / ssum;
        #pragma unroll
        for (int t = 0; t < Tdim; ++t) att[t] *= inv;
    }
    __syncthreads();

    // ---- txt_h accumulate: each thread owns 4 consecutive d ----
    const float* txtb = txt + (size_t)b * Tdim * Ddim;
    const int d0 = tid * 4;
    float4 th = {0.0f, 0.0f, 0.0f, 0.0f};
    #pragma unroll
    for (int t = 0; t < Tdim; ++t) {
        float a = att[t];
        float4 tv = *(const float4*)&txtb[(size_t)t * Ddim + d0];
        th.x = fmaf(a, tv.x, th.x);
        th.y = fmaf(a, tv.y, th.y);
        th.z = fmaf(a, tv.z, th.z);
        th.w = fmaf(a, tv.w, th.w);
    }

    // ---- cw/cb dots, block reduction ----
    float4 wcw = *(const float4*)&Wcw[d0];
    float4 wcb = *(const float4*)&Wcb[d0];
    float pcw = th.x * wcw.x + th.y * wcw.y + th.z * wcw.z + th.w * wcw.w;
    float pcb = th.x * wcb.x + th.y * wcb.y + th.z * wcb.z + th.w * wcb.w;
    #pragma unroll
    for (int off = 32; off; off >>= 1) {
        pcw += __shfl_xor(pcw, off, 64);
        pcb += __shfl_xor(pcb, off, 64);
    }
    if (lane == 0) { redw[wave] = pcw; redb[wave] = pcb; }
    __syncthreads();
    float cw = redw[0] + redw[1] + redw[2] + redw[3];
    float cb = redb[0] + redb[1] + redb[2] + redb[3];
    float w_s = fast_tanh(cw + bcw[0]);
    float b_s = fast_tanh(cb + bcb[0]);

    // ---- output ----
    const float* frow = feat + (size_t)blk * Ddim;
    float4 fv = *(const float4*)&frow[d0];
    float4 o;
    o.x = w_s * fv.x + b_s;
    o.y = w_s * fv.y + b_s;
    o.z = w_s * fv.z + b_s;
    o.w = w_s * fv.w + b_s;
    *(float4*)&out[(size_t)blk * Ddim + d0] = o;
}

// ---------------------------------------------------------------------------
extern "C" void kernel_launch(void* const* d_in, const int* in_sizes, int n_in,
                              void* d_out, int out_size, void* d_ws, size_t ws_size,
                              hipStream_t stream) {
    const float* features = (const float*)d_in[0];   // [B,F,D]
    // d_in[1] masks: unused
    const float* textual  = (const float*)d_in[2];   // [B,T,D]
    const int*   q_masks  = (const int*)d_in[3];     // [B,T]
    const float* Ws       = (const float*)d_in[4];   // [D,D]
    const float* W        = (const float*)d_in[5];   // [D,D]
    const float* wvec     = (const float*)d_in[6];   // [D,1]
    const float* bvec     = (const float*)d_in[7];   // [1,D]
    const float* Wcw      = (const float*)d_in[8];   // [1,D]
    const float* bcw      = (const float*)d_in[9];   // [1]
    const float* Wcb      = (const float*)d_in[10];  // [1,D]
    const float* bcb      = (const float*)d_in[11];  // [1]
    float* out = (float*)d_out;

    // workspace: feat_proj [2048,1024] then txt_proj+b [256,1024]  (9 MB)
    float* fp_ws = (float*)d_ws;
    float* tp_ws = fp_ws + (size_t)Bdim * Fdim * Ddim;

    const int M1 = Bdim * Fdim;   // 2048
    const int M2 = Bdim * Tdim;   // 256

    // feat_proj = features @ W
    gemm_f32<<<dim3(Ddim / BN, M1 / BM), 256, 0, stream>>>(
        features, W, fp_ws, nullptr, M1, Ddim, Ddim);
    // txt_proj = textual @ Ws + b
    gemm_f32<<<dim3(Ddim / BN, M2 / BM), 256, 0, stream>>>(
        textual, Ws, tp_ws, bvec, M2, Ddim, Ddim);
    // fused attention + conditioning
    attn_fused<<<Bdim * Fdim, 256, 0, stream>>>(
        features, textual, q_masks, fp_ws, tp_ws,
        wvec, Wcw, bcw, Wcb, bcb, out);
}

// Round 2
// 151.011 us; speedup vs baseline: 1.6199x; 1.6199x over previous
//
#include <hip/hip_runtime.h>
#include <math.h>

// Problem constants (SCDM_89318139888190)
#define Bdim 8
#define Fdim 256
#define Tdim 32
#define Ddim 1024
#define NEGV (-1e30f)

typedef unsigned short ushort;
using short8  = __attribute__((ext_vector_type(8))) short;   // 8 bf16 in 4 VGPRs
using floatx4 = __attribute__((ext_vector_type(4))) float;   // MFMA accumulator

__device__ __forceinline__ float fast_tanh(float x) {
    float e = __expf(2.0f * x);
    return 1.0f - 2.0f / (e + 1.0f);
}

__device__ __forceinline__ ushort f2bf(float f) {
    // round-to-nearest-even fp32 -> bf16 (inputs are finite normals)
    unsigned u = __float_as_uint(f);
    unsigned r = u + 0x7FFFu + ((u >> 16) & 1u);
    return (ushort)(r >> 16);
}

// ---------------------------------------------------------------------------
// prep 1: cast features [2048,1024] and textual [256,1024] fp32 -> bf16
// grid 2304 x 256 threads, 4 elems/thread
// ---------------------------------------------------------------------------
__global__ __launch_bounds__(256) void prep_cast(
    const float* __restrict__ feat, const float* __restrict__ txt,
    ushort* __restrict__ featB, ushort* __restrict__ txtB)
{
    const int blk = blockIdx.x;
    const float* in;
    ushort* out;
    int base;
    if (blk < Bdim * Fdim) { in = feat; out = featB; base = blk * Ddim; }
    else { in = txt; out = txtB; base = (blk - Bdim * Fdim) * Ddim; }
    const int i = base + threadIdx.x * 4;
    float4 v = *(const float4*)(in + i);
    ushort4 o;
    o.x = f2bf(v.x); o.y = f2bf(v.y); o.z = f2bf(v.z); o.w = f2bf(v.w);
    *(ushort4*)(out + i) = o;
}

// ---------------------------------------------------------------------------
// prep 2: W [K,N] fp32 -> W^T [N,K] bf16 (and same for Ws), 32x32 LDS tiles
// grid (32,32,2) x 256
// ---------------------------------------------------------------------------
__global__ __launch_bounds__(256) void prep_transpose(
    const float* __restrict__ W, const float* __restrict__ Ws,
    ushort* __restrict__ WtB, ushort* __restrict__ WstB)
{
    const float* in = blockIdx.z ? Ws : W;
    ushort* out = blockIdx.z ? WstB : WtB;
    __shared__ ushort tile[32][33];
    const int bx = blockIdx.x * 32;   // col (n) base of input
    const int by = blockIdx.y * 32;   // row (k) base of input
    const int tx = threadIdx.x & 31;
    const int tg = threadIdx.x >> 5;  // 0..7
    #pragma unroll
    for (int r = tg; r < 32; r += 8)
        tile[r][tx] = f2bf(in[(size_t)(by + r) * Ddim + bx + tx]);
    __syncthreads();
    #pragma unroll
    for (int r = tg; r < 32; r += 8)
        out[(size_t)(bx + r) * Ddim + by + tx] = tile[tx][r];
}

// ---------------------------------------------------------------------------
// bf16 MFMA GEMM, both projections in one dispatch.
//   C[M,N] = A[M,K](bf16) * Bt[N,K](bf16)^T  (+bias for the txt projection)
// 64x64 block tile, BK=32, 4 waves, each wave = 32x32 quadrant via 2x2
// mfma_f32_16x16x32_bf16. blockIdx.y 0..31 -> feat_proj rows; 32..35 ->
// txt_proj rows.
// Fragment layouts (guide-verified, m89/m120):
//   A: lane holds A[m = lane&15][k = (lane>>4)*8 + j], j=0..7
//   B: lane holds B[k = (lane>>4)*8 + j][n = lane&15]  (== Bt[n][k] contiguous)
//   C/D: col = lane&15, row = (lane>>4)*4 + reg
// ---------------------------------------------------------------------------
#define GBK 32

__global__ __launch_bounds__(256) void gemm_dual(
    const ushort* __restrict__ A1, const ushort* __restrict__ Bt1, float* __restrict__ C1,
    const ushort* __restrict__ A2, const ushort* __restrict__ Bt2, float* __restrict__ C2,
    const float* __restrict__ bias2)
{
    const int K = Ddim, N = Ddim;
    const int by = blockIdx.y;
    const ushort* A; const ushort* Bt; float* C; const float* bias; int m0;
    if (by < 32) { A = A1; Bt = Bt1; C = C1; bias = nullptr; m0 = by * 64; }
    else         { A = A2; Bt = Bt2; C = C2; bias = bias2;  m0 = (by - 32) * 64; }
    const int n0 = blockIdx.x * 64;

    __shared__ __align__(16) ushort As[64 * GBK];
    __shared__ __align__(16) ushort Bs[64 * GBK];

    const int tid  = threadIdx.x;
    const int l    = tid & 63;
    const int wave = tid >> 6;

    // staging: 256 threads x 8 bf16 (16B) = 64x32 tile exactly
    const int srow = tid >> 2;
    const int scol = (tid & 3) * 8;

    const int wm = (wave >> 1) * 32;   // wave's row quadrant
    const int wn = (wave & 1) * 32;    // wave's col quadrant

    floatx4 acc[2][2];
    #pragma unroll
    for (int i = 0; i < 2; ++i)
        #pragma unroll
        for (int j = 0; j < 2; ++j)
            acc[i][j] = (floatx4){0.0f, 0.0f, 0.0f, 0.0f};

    const int lm = l & 15;        // fragment row/col within 16
    const int lk = (l >> 4) * 8;  // fragment k base

    for (int k0 = 0; k0 < K; k0 += GBK) {
        uint4 av = *(const uint4*)(A  + (size_t)(m0 + srow) * K + k0 + scol);
        uint4 bv = *(const uint4*)(Bt + (size_t)(n0 + srow) * K + k0 + scol);
        __syncthreads();   // previous iteration's LDS reads complete
        *(uint4*)&As[srow * GBK + scol] = av;
        *(uint4*)&Bs[srow * GBK + scol] = bv;
        __syncthreads();

        short8 af0 = *(const short8*)&As[(wm + lm) * GBK + lk];
        short8 af1 = *(const short8*)&As[(wm + 16 + lm) * GBK + lk];
        short8 bf0 = *(const short8*)&Bs[(wn + lm) * GBK + lk];
        short8 bf1 = *(const short8*)&Bs[(wn + 16 + lm) * GBK + lk];
        acc[0][0] = __builtin_amdgcn_mfma_f32_16x16x32_bf16(af0, bf0, acc[0][0], 0, 0, 0);
        acc[0][1] = __builtin_amdgcn_mfma_f32_16x16x32_bf16(af0, bf1, acc[0][1], 0, 0, 0);
        acc[1][0] = __builtin_amdgcn_mfma_f32_16x16x32_bf16(af1, bf0, acc[1][0], 0, 0, 0);
        acc[1][1] = __builtin_amdgcn_mfma_f32_16x16x32_bf16(af1, bf1, acc[1][1], 0, 0, 0);
    }

    const int rowq = (l >> 4) * 4;
    #pragma unroll
    for (int im = 0; im < 2; ++im) {
        #pragma unroll
        for (int in_ = 0; in_ < 2; ++in_) {
            const int col = n0 + wn + in_ * 16 + lm;
            float badd = (bias != nullptr) ? bias[col] : 0.0f;
            #pragma unroll
            for (int r = 0; r < 4; ++r) {
                const int row = m0 + wm + im * 16 + rowq + r;
                C[(size_t)row * N + col] = acc[im][in_][r] + badd;
            }
        }
    }
}

// ---------------------------------------------------------------------------
// Fused additive-attention + conditioning. One block per (b,f). (unchanged)
// ---------------------------------------------------------------------------
__global__ __launch_bounds__(256) void attn_fused(
    const float* __restrict__ feat,   // [B,F,D]
    const float* __restrict__ txt,    // [B,T,D]
    const int*   __restrict__ qmask,  // [B,T]
    const float* __restrict__ fp,     // [B*F,D] feat_proj
    const float* __restrict__ tp,     // [B*T,D] txt_proj + b
    const float* __restrict__ wvec,   // [D]
    const float* __restrict__ Wcw,    // [D]
    const float* __restrict__ bcw,    // [1]
    const float* __restrict__ Wcb,    // [D]
    const float* __restrict__ bcb,    // [1]
    float* __restrict__ out)          // [B,F,D]
{
    const int blk  = blockIdx.x;          // 0 .. B*F-1
    const int b    = blk >> 8;            // / Fdim (256)
    const int tid  = threadIdx.x;
    const int lane = tid & 63;
    const int wave = tid >> 6;            // 0..3

    __shared__ float fp_lds[Ddim];
    __shared__ float w_lds[Ddim];
    __shared__ float rho[Tdim];
    __shared__ float att[Tdim];
    __shared__ float redw[4];
    __shared__ float redb[4];

    const float* fprow = fp + (size_t)blk * Ddim;
    {
        int d = tid * 4;
        *(float4*)&fp_lds[d] = *(const float4*)&fprow[d];
        *(float4*)&w_lds[d]  = *(const float4*)&wvec[d];
    }
    __syncthreads();

    const float* tpb = tp + (size_t)b * Tdim * Ddim;
    #pragma unroll
    for (int tt = 0; tt < 8; ++tt) {
        const int t = wave * 8 + tt;
        const float* tr = tpb + (size_t)t * Ddim;
        float s = 0.0f;
        #pragma unroll
        for (int it = 0; it < 4; ++it) {
            int d0 = lane * 4 + it * 256;
            float4 tv = *(const float4*)&tr[d0];
            float4 fv = *(const float4*)&fp_lds[d0];
            float4 wv = *(const float4*)&w_lds[d0];
            s = fmaf(fast_tanh(tv.x + fv.x), wv.x, s);
            s = fmaf(fast_tanh(tv.y + fv.y), wv.y, s);
            s = fmaf(fast_tanh(tv.z + fv.z), wv.z, s);
            s = fmaf(fast_tanh(tv.w + fv.w), wv.w, s);
        }
        #pragma unroll
        for (int off = 32; off; off >>= 1) s += __shfl_xor(s, off, 64);
        if (lane == 0) rho[t] = s;
    }
    __syncthreads();

    if (tid < Tdim) {
        float q = (float)qmask[b * Tdim + tid];
        rho[tid] += (1.0f - q) * NEGV;
    }
    __syncthreads();
    if (tid == 0) {
        float m = -3.4e38f;
        #pragma unroll
        for (int t = 0; t < Tdim; ++t) m = fmaxf(m, rho[t]);
        float ssum = 0.0f;
        #pragma unroll
        for (int t = 0; t < Tdim; ++t) {
            float e = __expf(rho[t] - m);
            att[t] = e;
            ssum += e;
        }
        float inv = 1.0f / ssum;
        #pragma unroll
        for (int t = 0; t < Tdim; ++t) att[t] *= inv;
    }
    __syncthreads();

    const float* txtb = txt + (size_t)b * Tdim * Ddim;
    const int d0 = tid * 4;
    float4 th = {0.0f, 0.0f, 0.0f, 0.0f};
    #pragma unroll
    for (int t = 0; t < Tdim; ++t) {
        float a = att[t];
        float4 tv = *(const float4*)&txtb[(size_t)t * Ddim + d0];
        th.x = fmaf(a, tv.x, th.x);
        th.y = fmaf(a, tv.y, th.y);
        th.z = fmaf(a, tv.z, th.z);
        th.w = fmaf(a, tv.w, th.w);
    }

    float4 wcw = *(const float4*)&Wcw[d0];
    float4 wcb = *(const float4*)&Wcb[d0];
    float pcw = th.x * wcw.x + th.y * wcw.y + th.z * wcw.z + th.w * wcw.w;
    float pcb = th.x * wcb.x + th.y * wcb.y + th.z * wcb.z + th.w * wcb.w;
    #pragma unroll
    for (int off = 32; off; off >>= 1) {
        pcw += __shfl_xor(pcw, off, 64);
        pcb += __shfl_xor(pcb, off, 64);
    }
    if (lane == 0) { redw[wave] = pcw; redb[wave] = pcb; }
    __syncthreads();
    float cw = redw[0] + redw[1] + redw[2] + redw[3];
    float cb = redb[0] + redb[1] + redb[2] + redb[3];
    float w_s = fast_tanh(cw + bcw[0]);
    float b_s = fast_tanh(cb + bcb[0]);

    const float* frow = feat + (size_t)blk * Ddim;
    float4 fv = *(const float4*)&frow[d0];
    float4 o;
    o.x = w_s * fv.x + b_s;
    o.y = w_s * fv.y + b_s;
    o.z = w_s * fv.z + b_s;
    o.w = w_s * fv.w + b_s;
    *(float4*)&out[(size_t)blk * Ddim + d0] = o;
}

// ---------------------------------------------------------------------------
extern "C" void kernel_launch(void* const* d_in, const int* in_sizes, int n_in,
                              void* d_out, int out_size, void* d_ws, size_t ws_size,
                              hipStream_t stream) {
    const float* features = (const float*)d_in[0];   // [B,F,D]
    const float* textual  = (const float*)d_in[2];   // [B,T,D]
    const int*   q_masks  = (const int*)d_in[3];     // [B,T]
    const float* Ws       = (const float*)d_in[4];   // [D,D]
    const float* W        = (const float*)d_in[5];   // [D,D]
    const float* wvec     = (const float*)d_in[6];   // [D,1]
    const float* bvec     = (const float*)d_in[7];   // [1,D]
    const float* Wcw      = (const float*)d_in[8];   // [1,D]
    const float* bcw      = (const float*)d_in[9];   // [1]
    const float* Wcb      = (const float*)d_in[10];  // [1,D]
    const float* bcb      = (const float*)d_in[11];  // [1]
    float* out = (float*)d_out;

    // workspace layout (17.5 MB total)
    float*  fp_ws = (float*)d_ws;                          // 2048*1024 f32
    float*  tp_ws = fp_ws + (size_t)Bdim * Fdim * Ddim;    // 256*1024 f32
    ushort* featB = (ushort*)(tp_ws + (size_t)Bdim * Tdim * Ddim); // 2048*1024 bf16
    ushort* txtB  = featB + (size_t)Bdim * Fdim * Ddim;    // 256*1024 bf16
    ushort* WtB   = txtB + (size_t)Bdim * Tdim * Ddim;     // 1024*1024 bf16
    ushort* WstB  = WtB + (size_t)Ddim * Ddim;             // 1024*1024 bf16

    // 1. cast activations to bf16
    prep_cast<<<Bdim * Fdim + Bdim * Tdim, 256, 0, stream>>>(
        features, textual, featB, txtB);
    // 2. transpose+cast weights to bf16 [N,K]
    prep_transpose<<<dim3(32, 32, 2), 256, 0, stream>>>(W, Ws, WtB, WstB);
    // 3. both projections, one MFMA dispatch (y 0..31 feat, 32..35 txt+bias)
    gemm_dual<<<dim3(16, 36), 256, 0, stream>>>(
        featB, WtB, fp_ws, txtB, WstB, tp_ws, bvec);
    // 4. fused attention + conditioning
    attn_fused<<<Bdim * Fdim, 256, 0, stream>>>(
        features, textual, q_masks, fp_ws, tp_ws,
        wvec, Wcw, bcw, Wcb, bcb, out);
}

// Round 3
// 128.186 us; speedup vs baseline: 1.9083x; 1.1781x over previous
//
#include <hip/hip_runtime.h>
#include <math.h>

// Problem constants (SCDM_89318139888190)
#define Bdim 8
#define Fdim 256
#define Tdim 32
#define Ddim 1024
#define NEGV (-1e30f)
#define TANH_SCALE 2.8853900817779268f   // 2*log2(e): tanh(x)=1-2*rcp(exp2(c*x)+1)
#define LOG2E 1.4426950408889634f

typedef unsigned short ushort;
using short8  = __attribute__((ext_vector_type(8))) short;   // 8 bf16 in 4 VGPRs
using floatx4 = __attribute__((ext_vector_type(4))) float;   // MFMA accumulator

__device__ __forceinline__ float fexp2(float x) { return __builtin_amdgcn_exp2f(x); }
__device__ __forceinline__ float frcp(float x)  { return __builtin_amdgcn_rcpf(x); }

// tanh via 2 transcendentals, ~1e-6 rel err (x NOT pre-scaled)
__device__ __forceinline__ float fast_tanh(float x) {
    return 1.0f - 2.0f * frcp(fexp2(x * TANH_SCALE) + 1.0f);
}

__device__ __forceinline__ ushort f2bf(float f) {
    unsigned u = __float_as_uint(f);
    unsigned r = u + 0x7FFFu + ((u >> 16) & 1u);
    return (ushort)(r >> 16);
}

// ---------------------------------------------------------------------------
// prep (merged): blocks [0,2304) cast feat/txt rows to bf16;
// blocks [2304, 2304+2048) transpose+cast W / Ws 32x32 tiles.
// ---------------------------------------------------------------------------
__global__ __launch_bounds__(256) void prep(
    const float* __restrict__ feat, const float* __restrict__ txt,
    const float* __restrict__ W, const float* __restrict__ Ws,
    ushort* __restrict__ featB, ushort* __restrict__ txtB,
    ushort* __restrict__ WtB, ushort* __restrict__ WstB)
{
    __shared__ ushort tile[32][33];
    const int blk = blockIdx.x;
    const int NCAST = Bdim * Fdim + Bdim * Tdim;   // 2304
    if (blk < NCAST) {
        const float* in; ushort* out; int base;
        if (blk < Bdim * Fdim) { in = feat; out = featB; base = blk * Ddim; }
        else { in = txt; out = txtB; base = (blk - Bdim * Fdim) * Ddim; }
        const int i = base + threadIdx.x * 4;
        float4 v = *(const float4*)(in + i);
        ushort4 o;
        o.x = f2bf(v.x); o.y = f2bf(v.y); o.z = f2bf(v.z); o.w = f2bf(v.w);
        *(ushort4*)(out + i) = o;
    } else {
        int t = blk - NCAST;                      // 0..2047
        const float* in = (t < 1024) ? W : Ws;
        ushort* out = (t < 1024) ? WtB : WstB;
        t &= 1023;
        const int bx = (t & 31) * 32;             // col (n) base
        const int by = (t >> 5) * 32;             // row (k) base
        const int tx = threadIdx.x & 31;
        const int tg = threadIdx.x >> 5;
        #pragma unroll
        for (int r = tg; r < 32; r += 8)
            tile[r][tx] = f2bf(in[(size_t)(by + r) * Ddim + bx + tx]);
        __syncthreads();
        #pragma unroll
        for (int r = tg; r < 32; r += 8)
            out[(size_t)(bx + r) * Ddim + by + tx] = tile[tx][r];
    }
}

// ---------------------------------------------------------------------------
// bf16 MFMA GEMM, both projections in one dispatch, epilogue scales by
// TANH_SCALE (outputs feed only the tanh argument in attn).
// 64x64 tile, GBK=32, register-prefetch software pipeline, XOR-swizzled LDS.
// ---------------------------------------------------------------------------
#define GBK 32

// swizzle 16B chunks within a 64B row to spread banks: row stride 64B = 16
// banks; chunk' = chunk ^ ((row>>1)&3) makes same-chunk reads across rows
// land 2-way max (free per m136).
__device__ __forceinline__ int swz(int row, int kUsh) {
    int ch = (kUsh >> 3) ^ ((row >> 1) & 3);
    return row * GBK + ch * 8 + (kUsh & 7);
}

__global__ __launch_bounds__(256) void gemm_dual(
    const ushort* __restrict__ A1, const ushort* __restrict__ Bt1, float* __restrict__ C1,
    const ushort* __restrict__ A2, const ushort* __restrict__ Bt2, float* __restrict__ C2,
    const float* __restrict__ bias2)
{
    const int K = Ddim, N = Ddim;
    const int by = blockIdx.y;
    const ushort* A; const ushort* Bt; float* C; const float* bias; int m0;
    if (by < 32) { A = A1; Bt = Bt1; C = C1; bias = nullptr; m0 = by * 64; }
    else         { A = A2; Bt = Bt2; C = C2; bias = bias2;  m0 = (by - 32) * 64; }
    const int n0 = blockIdx.x * 64;

    __shared__ __align__(16) ushort As[64 * GBK];
    __shared__ __align__(16) ushort Bs[64 * GBK];

    const int tid  = threadIdx.x;
    const int l    = tid & 63;
    const int wave = tid >> 6;

    const int srow = tid >> 2;          // staging row
    const int scol = (tid & 3) * 8;     // staging k (ushort)

    const int wm = (wave >> 1) * 32;
    const int wn = (wave & 1) * 32;

    floatx4 acc[2][2];
    #pragma unroll
    for (int i = 0; i < 2; ++i)
        #pragma unroll
        for (int j = 0; j < 2; ++j)
            acc[i][j] = (floatx4){0.0f, 0.0f, 0.0f, 0.0f};

    const int lm = l & 15;
    const int lk = (l >> 4) * 8;

    const ushort* aptr = A  + (size_t)(m0 + srow) * K + scol;
    const ushort* bptr = Bt + (size_t)(n0 + srow) * K + scol;

    // software pipeline: registers hold tile k0 while LDS holds k0-32
    uint4 av = *(const uint4*)(aptr);
    uint4 bv = *(const uint4*)(bptr);

    for (int k0 = 0; k0 < K; k0 += GBK) {
        __syncthreads();   // prior iteration's frag reads complete
        *(uint4*)&As[swz(srow, scol)] = av;
        *(uint4*)&Bs[swz(srow, scol)] = bv;
        __syncthreads();

        int kn = k0 + GBK; if (kn >= K) kn = 0;   // dummy wrap on last iter
        av = *(const uint4*)(aptr + kn);
        bv = *(const uint4*)(bptr + kn);

        short8 af0 = *(const short8*)&As[swz(wm + lm,      lk)];
        short8 af1 = *(const short8*)&As[swz(wm + 16 + lm, lk)];
        short8 bf0 = *(const short8*)&Bs[swz(wn + lm,      lk)];
        short8 bf1 = *(const short8*)&Bs[swz(wn + 16 + lm, lk)];
        acc[0][0] = __builtin_amdgcn_mfma_f32_16x16x32_bf16(af0, bf0, acc[0][0], 0, 0, 0);
        acc[0][1] = __builtin_amdgcn_mfma_f32_16x16x32_bf16(af0, bf1, acc[0][1], 0, 0, 0);
        acc[1][0] = __builtin_amdgcn_mfma_f32_16x16x32_bf16(af1, bf0, acc[1][0], 0, 0, 0);
        acc[1][1] = __builtin_amdgcn_mfma_f32_16x16x32_bf16(af1, bf1, acc[1][1], 0, 0, 0);
    }

    const int rowq = (l >> 4) * 4;
    #pragma unroll
    for (int im = 0; im < 2; ++im) {
        #pragma unroll
        for (int in_ = 0; in_ < 2; ++in_) {
            const int col = n0 + wn + in_ * 16 + lm;
            float badd = (bias != nullptr) ? bias[col] : 0.0f;
            #pragma unroll
            for (int r = 0; r < 4; ++r) {
                const int row = m0 + wm + im * 16 + rowq + r;
                C[(size_t)row * N + col] = (acc[im][in_][r] + badd) * TANH_SCALE;
            }
        }
    }
}

// ---------------------------------------------------------------------------
// attn v2: one block per 2 f-rows (NF=2). fp/w fragments in registers,
// tanh = 1-2*rcp(exp2(arg)+1) with arg pre-scaled in the GEMM epilogue.
// rho = sumw - 2*sum(w*r). Wave-parallel softmax.
// ---------------------------------------------------------------------------
__global__ __launch_bounds__(256, 4) void attn_fused(
    const float* __restrict__ feat,   // [B,F,D] raw
    const float* __restrict__ txt,    // [B,T,D] raw
    const int*   __restrict__ qmask,  // [B,T]
    const float* __restrict__ fp_s,   // [B*F,D]  feat_proj * c
    const float* __restrict__ tp_s,   // [B*T,D]  (txt_proj+b) * c
    const float* __restrict__ wvec,   // [D]
    const float* __restrict__ Wcw,    // [D]
    const float* __restrict__ bcw,    // [1]
    const float* __restrict__ Wcb,    // [D]
    const float* __restrict__ bcb,    // [1]
    float* __restrict__ out)          // [B,F,D]
{
    const int blk  = blockIdx.x;          // 0..1023
    const int f0   = blk * 2;             // first of two f rows (global idx)
    const int b    = f0 >> 8;             // / Fdim
    const int tid  = threadIdx.x;
    const int lane = tid & 63;
    const int wave = tid >> 6;

    __shared__ float srho[2][Tdim];
    __shared__ float satt[2][Tdim];
    __shared__ float sred[4][4];

    // per-lane d-slice: d(it) = lane*4 + it*256 (full D per wave)
    float4 wv[4], fva[4], fvb[4];
    const float* fr0 = fp_s + (size_t)f0 * Ddim;
    const float* fr1 = fr0 + Ddim;
    #pragma unroll
    for (int it = 0; it < 4; ++it) {
        const int d = lane * 4 + it * 256;
        wv[it]  = *(const float4*)&wvec[d];
        fva[it] = *(const float4*)&fr0[d];
        fvb[it] = *(const float4*)&fr1[d];
    }
    float sumw = 0.0f;
    #pragma unroll
    for (int it = 0; it < 4; ++it)
        sumw += wv[it].x + wv[it].y + wv[it].z + wv[it].w;
    #pragma unroll
    for (int off = 32; off; off >>= 1) sumw += __shfl_xor(sumw, off, 64);

    // ---- phase 1: logits. wave handles t = wave*8 + tt ----
    const float* tpb = tp_s + (size_t)b * Tdim * Ddim;
    for (int tt = 0; tt < 8; ++tt) {
        const int t = wave * 8 + tt;
        const float* tr = tpb + (size_t)t * Ddim;
        float s0a = 0.0f, s0b = 0.0f, s1a = 0.0f, s1b = 0.0f;  // 2 accs/f for ILP
        #pragma unroll
        for (int it = 0; it < 4; ++it) {
            const int d = lane * 4 + it * 256;
            float4 tv = *(const float4*)&tr[d];
            float e, r;
            e = fexp2(tv.x + fva[it].x); r = frcp(e + 1.0f); s0a = fmaf(wv[it].x, r, s0a);
            e = fexp2(tv.y + fva[it].y); r = frcp(e + 1.0f); s0b = fmaf(wv[it].y, r, s0b);
            e = fexp2(tv.z + fva[it].z); r = frcp(e + 1.0f); s0a = fmaf(wv[it].z, r, s0a);
            e = fexp2(tv.w + fva[it].w); r = frcp(e + 1.0f); s0b = fmaf(wv[it].w, r, s0b);
            e = fexp2(tv.x + fvb[it].x); r = frcp(e + 1.0f); s1a = fmaf(wv[it].x, r, s1a);
            e = fexp2(tv.y + fvb[it].y); r = frcp(e + 1.0f); s1b = fmaf(wv[it].y, r, s1b);
            e = fexp2(tv.z + fvb[it].z); r = frcp(e + 1.0f); s1a = fmaf(wv[it].z, r, s1a);
            e = fexp2(tv.w + fvb[it].w); r = frcp(e + 1.0f); s1b = fmaf(wv[it].w, r, s1b);
        }
        float s0 = s0a + s0b, s1 = s1a + s1b;
        #pragma unroll
        for (int off = 32; off; off >>= 1) {
            s0 += __shfl_xor(s0, off, 64);
            s1 += __shfl_xor(s1, off, 64);
        }
        if (lane == 0) { srho[0][t] = s0; srho[1][t] = s1; }
    }
    __syncthreads();

    // ---- softmax: wave 0, 32 lanes per f-row ----
    if (wave == 0) {
        const int f = lane >> 5, t = lane & 31;
        const float q = (float)qmask[b * Tdim + t];
        float L = sumw - 2.0f * srho[f][t] + (1.0f - q) * NEGV;
        float m = L;
        #pragma unroll
        for (int off = 16; off; off >>= 1) m = fmaxf(m, __shfl_xor(m, off, 64));
        float e = fexp2((L - m) * LOG2E);
        float ssum = e;
        #pragma unroll
        for (int off = 16; off; off >>= 1) ssum += __shfl_xor(ssum, off, 64);
        satt[f][t] = e * frcp(ssum);
    }
    __syncthreads();

    // ---- phase 2: txt_h for both f rows; thread owns d0 = tid*4 ----
    const float* txtb = txt + (size_t)b * Tdim * Ddim;
    const int d0 = tid * 4;
    float4 th0 = {0,0,0,0}, th1 = {0,0,0,0};
    #pragma unroll 8
    for (int t = 0; t < Tdim; ++t) {
        float4 tv = *(const float4*)&txtb[(size_t)t * Ddim + d0];
        const float a0 = satt[0][t], a1 = satt[1][t];
        th0.x = fmaf(a0, tv.x, th0.x); th0.y = fmaf(a0, tv.y, th0.y);
        th0.z = fmaf(a0, tv.z, th0.z); th0.w = fmaf(a0, tv.w, th0.w);
        th1.x = fmaf(a1, tv.x, th1.x); th1.y = fmaf(a1, tv.y, th1.y);
        th1.z = fmaf(a1, tv.z, th1.z); th1.w = fmaf(a1, tv.w, th1.w);
    }

    float4 wcw = *(const float4*)&Wcw[d0];
    float4 wcb = *(const float4*)&Wcb[d0];
    float p00 = th0.x*wcw.x + th0.y*wcw.y + th0.z*wcw.z + th0.w*wcw.w;
    float p01 = th0.x*wcb.x + th0.y*wcb.y + th0.z*wcb.z + th0.w*wcb.w;
    float p10 = th1.x*wcw.x + th1.y*wcw.y + th1.z*wcw.z + th1.w*wcw.w;
    float p11 = th1.x*wcb.x + th1.y*wcb.y + th1.z*wcb.z + th1.w*wcb.w;
    #pragma unroll
    for (int off = 32; off; off >>= 1) {
        p00 += __shfl_xor(p00, off, 64);
        p01 += __shfl_xor(p01, off, 64);
        p10 += __shfl_xor(p10, off, 64);
        p11 += __shfl_xor(p11, off, 64);
    }
    if (lane == 0) {
        sred[wave][0] = p00; sred[wave][1] = p01;
        sred[wave][2] = p10; sred[wave][3] = p11;
    }
    __syncthreads();
    const float c00 = sred[0][0] + sred[1][0] + sred[2][0] + sred[3][0];
    const float c01 = sred[0][1] + sred[1][1] + sred[2][1] + sred[3][1];
    const float c10 = sred[0][2] + sred[1][2] + sred[2][2] + sred[3][2];
    const float c11 = sred[0][3] + sred[1][3] + sred[2][3] + sred[3][3];
    const float ws0 = fast_tanh(c00 + bcw[0]);
    const float bs0 = fast_tanh(c01 + bcb[0]);
    const float ws1 = fast_tanh(c10 + bcw[0]);
    const float bs1 = fast_tanh(c11 + bcb[0]);

    // ---- output: both f rows ----
    const float* ft0 = feat + (size_t)f0 * Ddim;
    float4 v0 = *(const float4*)&ft0[d0];
    float4 v1 = *(const float4*)&ft0[Ddim + d0];
    float4 o0, o1;
    o0.x = fmaf(ws0, v0.x, bs0); o0.y = fmaf(ws0, v0.y, bs0);
    o0.z = fmaf(ws0, v0.z, bs0); o0.w = fmaf(ws0, v0.w, bs0);
    o1.x = fmaf(ws1, v1.x, bs1); o1.y = fmaf(ws1, v1.y, bs1);
    o1.z = fmaf(ws1, v1.z, bs1); o1.w = fmaf(ws1, v1.w, bs1);
    *(float4*)&out[(size_t)f0 * Ddim + d0] = o0;
    *(float4*)&out[(size_t)f0 * Ddim + Ddim + d0] = o1;
}

// ---------------------------------------------------------------------------
extern "C" void kernel_launch(void* const* d_in, const int* in_sizes, int n_in,
                              void* d_out, int out_size, void* d_ws, size_t ws_size,
                              hipStream_t stream) {
    const float* features = (const float*)d_in[0];   // [B,F,D]
    const float* textual  = (const float*)d_in[2];   // [B,T,D]
    const int*   q_masks  = (const int*)d_in[3];     // [B,T]
    const float* Ws       = (const float*)d_in[4];   // [D,D]
    const float* W        = (const float*)d_in[5];   // [D,D]
    const float* wvec     = (const float*)d_in[6];   // [D,1]
    const float* bvec     = (const float*)d_in[7];   // [1,D]
    const float* Wcw      = (const float*)d_in[8];   // [1,D]
    const float* bcw      = (const float*)d_in[9];   // [1]
    const float* Wcb      = (const float*)d_in[10];  // [1,D]
    const float* bcb      = (const float*)d_in[11];  // [1]
    float* out = (float*)d_out;

    float*  fp_ws = (float*)d_ws;                          // 2048*1024 f32 (scaled)
    float*  tp_ws = fp_ws + (size_t)Bdim * Fdim * Ddim;    // 256*1024 f32 (scaled)
    ushort* featB = (ushort*)(tp_ws + (size_t)Bdim * Tdim * Ddim);
    ushort* txtB  = featB + (size_t)Bdim * Fdim * Ddim;
    ushort* WtB   = txtB + (size_t)Bdim * Tdim * Ddim;
    ushort* WstB  = WtB + (size_t)Ddim * Ddim;

    // 1. merged prep: cast activations + transpose/cast weights
    prep<<<Bdim * Fdim + Bdim * Tdim + 2048, 256, 0, stream>>>(
        features, textual, W, Ws, featB, txtB, WtB, WstB);
    // 2. both projections, one MFMA dispatch, epilogue *TANH_SCALE
    gemm_dual<<<dim3(16, 36), 256, 0, stream>>>(
        featB, WtB, fp_ws, txtB, WstB, tp_ws, bvec);
    // 3. fused attention + conditioning (2 f-rows per block)
    attn_fused<<<(Bdim * Fdim) / 2, 256, 0, stream>>>(
        features, textual, q_masks, fp_ws, tp_ws,
        wvec, Wcw, bcw, Wcb, bcb, out);
}